// Round 2
// baseline (1997.131 us; speedup 1.0000x reference)
//
#include <hip/hip_runtime.h>
#include <hip/hip_bf16.h>
#include <stdint.h>

#define BB   2
#define CC   256
#define NN   32768
#define DD   4
#define HH   256
#define WW   256
#define HWC  65536
#define NGG  3

typedef __attribute__((ext_vector_type(8))) short short8;
typedef __attribute__((ext_vector_type(4))) short short4v;
typedef __attribute__((ext_vector_type(4))) float f32x4;

__device__ __forceinline__ short f2bf(float f){
  union { float f; uint32_t u; } v; v.f = f;
  uint32_t u = v.u;
  uint32_t r = (u + 0x7fffu + ((u >> 16) & 1u)) >> 16;
  return (short)r;
}
__device__ __forceinline__ float bf2f(short s){
  union { uint32_t u; float f; } v; v.u = ((uint32_t)(uint16_t)s) << 16;
  return v.f;
}

// ---------------- counts / weights ----------------
__global__ __launch_bounds__(256) void count_kernel(const int* cell_ind, const float* occ, float* counts){
  int idx = blockIdx.x * 256 + threadIdx.x;      // over B*NG*N
  int n  = idx & (NN - 1);
  int bg = idx >> 15;                            // b*NG+g
  int b  = bg / NGG;
  atomicAdd(&counts[(size_t)bg * HWC + cell_ind[idx]], occ[(size_t)b * NN + n]);
}

__global__ __launch_bounds__(256) void weight_kernel(const int* cell_ind, const float* occ,
                                                     const float* counts, float* wts){
  int idx = blockIdx.x * 256 + threadIdx.x;
  int n  = idx & (NN - 1);
  int bg = idx >> 15;
  int b  = bg / NGG;
  float o = occ[(size_t)b * NN + n];
  float cnt = counts[(size_t)bg * HWC + cell_ind[idx]];
  wts[idx] = o / (cnt * o + 1e-6f);
}

// ---------------- BN stats -> per-channel scale/bias ----------------
// normalized = x * sOut[c] + tOut[c]
__global__ __launch_bounds__(256) void bnstats_kernel(const float* tok, const float* gamma,
                                                      const float* beta, float* sOut, float* tOut){
  int c = blockIdx.x;
  int t = threadIdx.x;
  float s = 0.f, sq = 0.f;
  for(int b = 0; b < BB; b++){
    const float4* p = (const float4*)(tok + ((size_t)b * CC + c) * NN);
    for(int i = t; i < NN / 4; i += 256){
      float4 v = p[i];
      s  += v.x + v.y + v.z + v.w;
      sq += v.x * v.x + v.y * v.y + v.z * v.z + v.w * v.w;
    }
  }
  __shared__ float rs[256], rq[256];
  rs[t] = s; rq[t] = sq;
  __syncthreads();
  for(int off = 128; off > 0; off >>= 1){
    if(t < off){ rs[t] += rs[t + off]; rq[t] += rq[t + off]; }
    __syncthreads();
  }
  if(t == 0){
    float m    = rs[0] / (float)(BB * NN);
    float var  = rq[0] / (float)(BB * NN) - m * m;
    float rstd = rsqrtf(var + 1e-5f);
    float g = gamma[c];
    sOut[c] = rstd * g;
    tOut[c] = beta[c] - m * rstd * g;
  }
}

// ---------------- scatter (normalize + weight + atomic into grid) ----------------
__global__ __launch_bounds__(256) void scatter_kernel(const float* tok, const int* cell_ind,
                                                      const float* wts, const float* sA, const float* tA,
                                                      float* gridA, int g){
  int blk = blockIdx.x;                 // B*N/64
  int b   = blk >> 9;
  int n0  = (blk & 511) << 6;
  int t   = threadIdx.x;
  __shared__ float lds[256 * 65];
  __shared__ int   cellL[64];
  __shared__ float wL[64];
  if(t < 64){
    cellL[t] = cell_ind[((size_t)b * NGG + g) * NN + n0 + t];
    wL[t]    = wts[((size_t)b * NGG + g) * NN + n0 + t];
  }
  // stage + normalize: lds[c][p], p = point within 64
  int pf = (t & 15) * 4;
  for(int i = 0; i < 16; i++){
    int c = (t >> 4) + 16 * i;
    float s  = sA[c];
    float tt = tA[c];
    float4 v = *(const float4*)(tok + ((size_t)b * CC + c) * NN + n0 + pf);
    lds[c * 65 + pf + 0] = v.x * s + tt;
    lds[c * 65 + pf + 1] = v.y * s + tt;
    lds[c * 65 + pf + 2] = v.z * s + tt;
    lds[c * 65 + pf + 3] = v.w * s + tt;
  }
  __syncthreads();
  for(int p = 0; p < 64; p++){
    int   cell = cellL[p];
    float wp   = wL[p];
    atomicAdd(&gridA[((size_t)b * HWC + cell) * CC + t], lds[t * 65 + p] * wp);
  }
}

// ---------------- fused dwconv1 + relu + dwconv2 ----------------
__global__ __launch_bounds__(256) void conv_kernel(const float* gridA, const float* k1, const float* b1,
                                                   const float* k2, const float* b2, short* gridB){
  int bi = blockIdx.x;                  // ((b*4 + cb)*32 + ty)*32 + tx
  int tx = bi & 31;
  int ty = (bi >> 5) & 31;
  int cb = (bi >> 10) & 3;
  int b  = bi >> 12;
  int t  = threadIdx.x;
  int c    = t & 63;
  int quad = t >> 6;
  int cc = cb * 64 + c;
  int y0 = ty * 8, x0 = tx * 8;
  __shared__ float ldsIn[144 * 64];     // 12x12 halo tile
  __shared__ float ldsMid[100 * 64];    // 10x10 mid tile
  float w1r[9], w2r[9];
  for(int i = 0; i < 9; i++){
    w1r[i] = k1[(size_t)cc * 9 + i];
    w2r[i] = k2[(size_t)cc * 9 + i];
  }
  float bb1 = b1[cc], bb2 = b2[cc];
  for(int i = 0; i < 36; i++){
    int cell = i * 4 + quad;
    int yy = y0 - 2 + cell / 12;
    int xx = x0 - 2 + cell % 12;
    float v = 0.f;
    if(yy >= 0 && yy < HH && xx >= 0 && xx < WW)
      v = gridA[((size_t)b * HWC + yy * WW + xx) * CC + cc];
    ldsIn[cell * 64 + c] = v;
  }
  __syncthreads();
  for(int i = 0; i < 25; i++){
    int cell = i * 4 + quad;
    int my = cell / 10, mx = cell % 10;
    int yy = y0 - 1 + my, xx = x0 - 1 + mx;
    float v = 0.f;
    if(yy >= 0 && yy < HH && xx >= 0 && xx < WW){
      float a = bb1;
      for(int ky = 0; ky < 3; ky++)
        for(int kx = 0; kx < 3; kx++)
          a += ldsIn[((my + ky) * 12 + (mx + kx)) * 64 + c] * w1r[ky * 3 + kx];
      v = fmaxf(a, 0.f);
    }
    ldsMid[cell * 64 + c] = v;
  }
  __syncthreads();
  for(int i = 0; i < 16; i++){
    int cell = i * 4 + quad;
    int oy = cell / 8, ox = cell % 8;
    float a = bb2;
    for(int ky = 0; ky < 3; ky++)
      for(int kx = 0; kx < 3; kx++)
        a += ldsMid[((oy + ky) * 10 + (ox + kx)) * 64 + c] * w2r[ky * 3 + kx];
    gridB[((size_t)b * HWC + (y0 + oy) * WW + (x0 + ox)) * CC + cc] = f2bf(a);
  }
}

// ---------------- gather + residual ----------------
__global__ __launch_bounds__(256) void gather_kernel(const float* tokIn, float* tokOut, const short* gridB,
                                                     const int* cell_ind, const float* occ,
                                                     const float* smScale, int g){
  int blk = blockIdx.x;
  int b   = blk >> 9;
  int n0  = (blk & 511) << 6;
  int t   = threadIdx.x;
  __shared__ float lds[256 * 65];
  __shared__ int   cellL[64];
  __shared__ float occL[64];
  if(t < 64){
    cellL[t] = cell_ind[((size_t)b * NGG + g) * NN + n0 + t];
    occL[t]  = occ[(size_t)b * NN + n0 + t];
  }
  __syncthreads();
  int half = t >> 7;
  int ch   = (t & 127) * 2;
  for(int it = 0; it < 32; it++){
    int p = it * 2 + half;
    int cell = cellL[p];
    uint32_t u = *(const uint32_t*)&gridB[((size_t)b * HWC + cell) * CC + ch];
    lds[ch * 65 + p]       = bf2f((short)(u & 0xffff));
    lds[(ch + 1) * 65 + p] = bf2f((short)(u >> 16));
  }
  __syncthreads();
  int pf = (t & 15) * 4;
  for(int i = 0; i < 16; i++){
    int c = (t >> 4) + 16 * i;
    float sc = smScale[c];
    size_t addr = ((size_t)b * CC + c) * NN + n0 + pf;
    float4 tv = *(const float4*)(tokIn + addr);
    float4 o;
    o.x = tv.x + sc * (occL[pf + 0] * lds[c * 65 + pf + 0]);
    o.y = tv.y + sc * (occL[pf + 1] * lds[c * 65 + pf + 1]);
    o.z = tv.z + sc * (occL[pf + 2] * lds[c * 65 + pf + 2]);
    o.w = tv.w + sc * (occL[pf + 3] * lds[c * 65 + pf + 3]);
    *(float4*)(tokOut + addr) = o;
  }
}

// ---------------- fold BN into W1/b1, convert W2 ----------------
__global__ __launch_bounds__(256) void fold_kernel(const float* w1, const float* bias1, const float* w2,
                                                   const float* sB, const float* tB,
                                                   short* W1f, short* W2f, float* b1f){
  int o = blockIdx.x;
  int t = threadIdx.x;
  float w = w1[(size_t)o * CC + t];
  W1f[o * CC + t] = f2bf(w * sB[t]);
  W2f[o * CC + t] = f2bf(w2[(size_t)o * CC + t]);
  __shared__ float red[256];
  red[t] = w * tB[t];
  __syncthreads();
  for(int off = 128; off > 0; off >>= 1){
    if(t < off) red[t] += red[t + off];
    __syncthreads();
  }
  if(t == 0) b1f[o] = bias1[o] + red[0];
}

// ---------------- fused MLP: tok += scale*(W2 @ relu(W1' @ tok + b1') + b2) ----------------
__global__ __launch_bounds__(256) void mlp_kernel(float* tok, const short* W1f, const float* b1f,
                                                  const short* W2f, const float* b2, const float* sc2){
  int blk = blockIdx.x;                  // B * N/64
  int b   = blk >> 9;
  int n0  = (blk & 511) << 6;
  int t   = threadIdx.x;
  int w   = t >> 6;
  int l   = t & 63;
  __shared__ short ldsX[64 * 264];       // [n][c], bf16, +8 pad
  __shared__ short ldsH[64 * 264];       // [n][o], bf16, +8 pad
  float* tb = tok + (size_t)b * CC * NN;

  // stage X tile (64 tokens x 256 channels), transpose 4x4 in regs
  {
    int nb = t & 15;
    int cbq = t >> 4;
    for(int i = 0; i < 4; i++){
      int c0 = cbq * 4 + 64 * i;
      float4 v0 = *(const float4*)(tb + (size_t)(c0 + 0) * NN + n0 + nb * 4);
      float4 v1 = *(const float4*)(tb + (size_t)(c0 + 1) * NN + n0 + nb * 4);
      float4 v2 = *(const float4*)(tb + (size_t)(c0 + 2) * NN + n0 + nb * 4);
      float4 v3 = *(const float4*)(tb + (size_t)(c0 + 3) * NN + n0 + nb * 4);
      short4v s0 = { f2bf(v0.x), f2bf(v1.x), f2bf(v2.x), f2bf(v3.x) };
      short4v s1 = { f2bf(v0.y), f2bf(v1.y), f2bf(v2.y), f2bf(v3.y) };
      short4v s2 = { f2bf(v0.z), f2bf(v1.z), f2bf(v2.z), f2bf(v3.z) };
      short4v s3 = { f2bf(v0.w), f2bf(v1.w), f2bf(v2.w), f2bf(v3.w) };
      *(short4v*)&ldsX[(nb * 4 + 0) * 264 + c0] = s0;
      *(short4v*)&ldsX[(nb * 4 + 1) * 264 + c0] = s1;
      *(short4v*)&ldsX[(nb * 4 + 2) * 264 + c0] = s2;
      *(short4v*)&ldsX[(nb * 4 + 3) * 264 + c0] = s3;
    }
  }
  __syncthreads();

  int ob = w * 64;
  int lr = l & 15;
  int lq = l >> 4;

  f32x4 acc[4][4];
  for(int m = 0; m < 4; m++)
    for(int nf = 0; nf < 4; nf++)
      acc[m][nf] = (f32x4){0.f, 0.f, 0.f, 0.f};
  for(int kk = 0; kk < 8; kk++){
    int kb = kk * 32 + lq * 8;
    short8 af[4], bfr[4];
    for(int m = 0; m < 4; m++)
      af[m] = *(const short8*)&W1f[(size_t)(ob + m * 16 + lr) * CC + kb];
    for(int nf = 0; nf < 4; nf++)
      bfr[nf] = *(const short8*)&ldsX[(nf * 16 + lr) * 264 + kb];
    for(int m = 0; m < 4; m++)
      for(int nf = 0; nf < 4; nf++)
        acc[m][nf] = __builtin_amdgcn_mfma_f32_16x16x32_bf16(af[m], bfr[nf], acc[m][nf], 0, 0, 0);
  }
  // epilogue 1: + b1', relu, bf16 -> ldsH[n][o]
  for(int m = 0; m < 4; m++){
    int o0 = ob + m * 16 + lq * 4;
    float bb0 = b1f[o0], bb1 = b1f[o0 + 1], bb2 = b1f[o0 + 2], bb3 = b1f[o0 + 3];
    for(int nf = 0; nf < 4; nf++){
      int n = nf * 16 + lr;
      short4v hv = { f2bf(fmaxf(acc[m][nf][0] + bb0, 0.f)),
                     f2bf(fmaxf(acc[m][nf][1] + bb1, 0.f)),
                     f2bf(fmaxf(acc[m][nf][2] + bb2, 0.f)),
                     f2bf(fmaxf(acc[m][nf][3] + bb3, 0.f)) };
      *(short4v*)&ldsH[n * 264 + o0] = hv;
    }
  }
  __syncthreads();

  f32x4 acc2[4][4];
  for(int m = 0; m < 4; m++)
    for(int nf = 0; nf < 4; nf++)
      acc2[m][nf] = (f32x4){0.f, 0.f, 0.f, 0.f};
  for(int kk = 0; kk < 8; kk++){
    int kb = kk * 32 + lq * 8;
    short8 af[4], bfr[4];
    for(int m = 0; m < 4; m++)
      af[m] = *(const short8*)&W2f[(size_t)(ob + m * 16 + lr) * CC + kb];
    for(int nf = 0; nf < 4; nf++)
      bfr[nf] = *(const short8*)&ldsH[(nf * 16 + lr) * 264 + kb];
    for(int m = 0; m < 4; m++)
      for(int nf = 0; nf < 4; nf++)
        acc2[m][nf] = __builtin_amdgcn_mfma_f32_16x16x32_bf16(af[m], bfr[nf], acc2[m][nf], 0, 0, 0);
  }
  // epilogue 2: tok += sc2*(acc2 + b2)
  for(int m = 0; m < 4; m++){
    int o0 = ob + m * 16 + lq * 4;
    for(int r = 0; r < 4; r++){
      int o = o0 + r;
      float s  = sc2[o];
      float bb = b2[o];
      for(int nf = 0; nf < 4; nf++){
        int n = nf * 16 + lr;
        size_t addr = (size_t)o * NN + n0 + n;
        tb[addr] = tb[addr] + s * (acc2[m][nf][r] + bb);
      }
    }
  }
}

extern "C" void kernel_launch(void* const* d_in, const int* in_sizes, int n_in,
                              void* d_out, int out_size, void* d_ws, size_t ws_size,
                              hipStream_t stream) {
  const float* tokens   = (const float*)d_in[0];
  const int*   cell_ind = (const int*)d_in[1];
  const float* occ      = (const float*)d_in[2];
  const float* cm_gamma = (const float*)d_in[3];
  const float* cm_beta  = (const float*)d_in[4];
  const float* cm_w1    = (const float*)d_in[5];
  const float* cm_b1    = (const float*)d_in[6];
  const float* cm_w2    = (const float*)d_in[7];
  const float* cm_b2    = (const float*)d_in[8];
  const float* cm_scale = (const float*)d_in[9];
  const float* sm_gamma = (const float*)d_in[10];
  const float* sm_beta  = (const float*)d_in[11];
  const float* sm_k1    = (const float*)d_in[12];
  const float* sm_b1    = (const float*)d_in[13];
  const float* sm_k2    = (const float*)d_in[14];
  const float* sm_b2    = (const float*)d_in[15];
  const float* sm_scale = (const float*)d_in[16];
  float* out = (float*)d_out;
  (void)in_sizes; (void)n_in; (void)out_size; (void)ws_size;

  char* ws = (char*)d_ws;
  size_t off = 0;
  auto carve = [&](size_t bytes) -> void* {
    void* p = ws + off;
    off = (off + bytes + 255) & ~(size_t)255;
    return p;
  };
  float* counts = (float*)carve((size_t)BB * NGG * HWC * 4);
  float* wts    = (float*)carve((size_t)BB * NGG * NN * 4);
  float* sA  = (float*)carve(CC * 4);
  float* tA  = (float*)carve(CC * 4);
  float* sB  = (float*)carve(CC * 4);
  float* tB  = (float*)carve(CC * 4);
  float* b1f = (float*)carve(CC * 4);
  short* W1f = (short*)carve((size_t)CC * CC * 2);
  short* W2f = (short*)carve((size_t)CC * CC * 2);
  float* gridA = (float*)carve((size_t)BB * HWC * CC * 4);
  short* gridB = (short*)carve((size_t)BB * HWC * CC * 2);

  hipMemsetAsync(counts, 0, (size_t)BB * NGG * HWC * 4, stream);
  count_kernel<<<BB * NGG * NN / 256, 256, 0, stream>>>(cell_ind, occ, counts);
  weight_kernel<<<BB * NGG * NN / 256, 256, 0, stream>>>(cell_ind, occ, counts, wts);

  const float* tokCur = tokens;
  for(int d = 0; d < DD; d++){
    int g = d % NGG;
    bnstats_kernel<<<CC, 256, 0, stream>>>(tokCur, sm_gamma + d * CC, sm_beta + d * CC, sA, tA);
    hipMemsetAsync(gridA, 0, (size_t)BB * HWC * CC * 4, stream);
    scatter_kernel<<<BB * NN / 64, 256, 0, stream>>>(tokCur, cell_ind, wts, sA, tA, gridA, g);
    conv_kernel<<<BB * 4 * 32 * 32, 256, 0, stream>>>(gridA, sm_k1 + (size_t)d * CC * 9, sm_b1 + d * CC,
                                                      sm_k2 + (size_t)d * CC * 9, sm_b2 + d * CC, gridB);
    gather_kernel<<<BB * NN / 64, 256, 0, stream>>>(tokCur, out, gridB, cell_ind, occ,
                                                    sm_scale + d * CC, g);
    bnstats_kernel<<<CC, 256, 0, stream>>>(out, cm_gamma + d * CC, cm_beta + d * CC, sB, tB);
    fold_kernel<<<CC, 256, 0, stream>>>(cm_w1 + (size_t)d * CC * CC, cm_b1 + d * CC,
                                        cm_w2 + (size_t)d * CC * CC, sB, tB, W1f, W2f, b1f);
    mlp_kernel<<<BB * NN / 64, 256, 0, stream>>>(out, W1f, b1f, W2f, cm_b2 + d * CC, cm_scale + d * CC);
    tokCur = out;
  }
}

// Round 4
// 1217.023 us; speedup vs baseline: 1.6410x; 1.6410x over previous
//
#include <hip/hip_runtime.h>
#include <hip/hip_bf16.h>
#include <stdint.h>

#define BB   2
#define CC   256
#define NN   32768
#define DD   4
#define HH   256
#define WW   256
#define HWC  65536
#define NGG  3

typedef __attribute__((ext_vector_type(8))) short short8;
typedef __attribute__((ext_vector_type(4))) short short4v;
typedef __attribute__((ext_vector_type(4))) float f32x4;

__device__ __forceinline__ short f2bf(float f){
  union { float f; uint32_t u; } v; v.f = f;
  uint32_t u = v.u;
  uint32_t r = (u + 0x7fffu + ((u >> 16) & 1u)) >> 16;
  return (short)r;
}
__device__ __forceinline__ float bf2f(short s){
  union { uint32_t u; float f; } v; v.u = ((uint32_t)(uint16_t)s) << 16;
  return v.f;
}

// ---------------- counts / weights ----------------
__global__ __launch_bounds__(256) void count_kernel(const int* cell_ind, const float* occ, float* counts){
  int idx = blockIdx.x * 256 + threadIdx.x;      // over B*NG*N
  int n  = idx & (NN - 1);
  int bg = idx >> 15;                            // b*NG+g
  int b  = bg / NGG;
  atomicAdd(&counts[(size_t)bg * HWC + cell_ind[idx]], occ[(size_t)b * NN + n]);
}

__global__ __launch_bounds__(256) void weight_kernel(const int* cell_ind, const float* occ,
                                                     const float* counts, float* wts){
  int idx = blockIdx.x * 256 + threadIdx.x;
  int n  = idx & (NN - 1);
  int bg = idx >> 15;
  int b  = bg / NGG;
  float o = occ[(size_t)b * NN + n];
  float cnt = counts[(size_t)bg * HWC + cell_ind[idx]];
  wts[idx] = o / (cnt * o + 1e-6f);
}

// ---------------- BN stats -> per-channel scale/bias ----------------
// normalized = x * sOut[c] + tOut[c]
__global__ __launch_bounds__(256) void bnstats_kernel(const float* tok, const float* gamma,
                                                      const float* beta, float* sOut, float* tOut){
  int c = blockIdx.x;
  int t = threadIdx.x;
  float s = 0.f, sq = 0.f;
  for(int b = 0; b < BB; b++){
    const float4* p = (const float4*)(tok + ((size_t)b * CC + c) * NN);
    for(int i = t; i < NN / 4; i += 256){
      float4 v = p[i];
      s  += v.x + v.y + v.z + v.w;
      sq += v.x * v.x + v.y * v.y + v.z * v.z + v.w * v.w;
    }
  }
  __shared__ float rs[256], rq[256];
  rs[t] = s; rq[t] = sq;
  __syncthreads();
  for(int off = 128; off > 0; off >>= 1){
    if(t < off){ rs[t] += rs[t + off]; rq[t] += rq[t + off]; }
    __syncthreads();
  }
  if(t == 0){
    float m    = rs[0] / (float)(BB * NN);
    float var  = rq[0] / (float)(BB * NN) - m * m;
    float rstd = rsqrtf(var + 1e-5f);
    float g = gamma[c];
    sOut[c] = rstd * g;
    tOut[c] = beta[c] - m * rstd * g;
  }
}

// ---------------- scatter (normalize + weight + atomic into grid) ----------------
__global__ __launch_bounds__(256) void scatter_kernel(const float* tok, const int* cell_ind,
                                                      const float* wts, const float* sA, const float* tA,
                                                      float* gridA, int g){
  int blk = blockIdx.x;                 // B*N/64
  int b   = blk >> 9;
  int n0  = (blk & 511) << 6;
  int t   = threadIdx.x;
  __shared__ float lds[256 * 65];
  __shared__ int   cellL[64];
  __shared__ float wL[64];
  if(t < 64){
    cellL[t] = cell_ind[((size_t)b * NGG + g) * NN + n0 + t];
    wL[t]    = wts[((size_t)b * NGG + g) * NN + n0 + t];
  }
  // stage + normalize: lds[c][p], p = point within 64
  int pf = (t & 15) * 4;
  for(int i = 0; i < 16; i++){
    int c = (t >> 4) + 16 * i;
    float s  = sA[c];
    float tt = tA[c];
    float4 v = *(const float4*)(tok + ((size_t)b * CC + c) * NN + n0 + pf);
    lds[c * 65 + pf + 0] = v.x * s + tt;
    lds[c * 65 + pf + 1] = v.y * s + tt;
    lds[c * 65 + pf + 2] = v.z * s + tt;
    lds[c * 65 + pf + 3] = v.w * s + tt;
  }
  __syncthreads();
  for(int p = 0; p < 64; p++){
    int   cell = cellL[p];
    float wp   = wL[p];
    atomicAdd(&gridA[((size_t)b * HWC + cell) * CC + t], lds[t * 65 + p] * wp);
  }
}

// ---------------- fused dwconv1 + relu + dwconv2, register rolling window, no LDS ----------------
__global__ __launch_bounds__(256) void conv_kernel(const float* __restrict__ gridA,
                                                   const float* __restrict__ k1, const float* __restrict__ b1,
                                                   const float* __restrict__ k2, const float* __restrict__ b2,
                                                   short* __restrict__ gridB){
  int bi = blockIdx.x;                  // b*1024 + ty*32 + tx
  int tx = bi & 31;
  int ty = (bi >> 5) & 31;
  int b  = bi >> 10;
  int c  = threadIdx.x;                 // 0..255 : one channel per thread
  int x0 = tx * 8, y0 = ty * 8;

  float w1r[9], w2r[9];
  #pragma unroll
  for(int i = 0; i < 9; i++){
    w1r[i] = k1[(size_t)c * 9 + i];
    w2r[i] = k2[(size_t)c * 9 + i];
  }
  float bb1 = b1[c], bb2 = b2[c];

  const float* gb = gridA + (size_t)b * HWC * CC + c;
  short*       ob = gridB + (size_t)b * HWC * CC + c;

  float in[3][12];                      // rolling 3 input rows (12 wide, halo 2)
  float mid[3][10];                     // rolling 3 mid rows (10 wide, halo 1)

  auto loadrow = [&](int slot, int yy){
    #pragma unroll
    for(int j = 0; j < 12; j++){
      int xx = x0 - 2 + j;
      float v = 0.f;
      if(yy >= 0 && yy < HH && xx >= 0 && xx < WW)
        v = gb[((size_t)yy * WW + xx) * CC];
      in[slot][j] = v;
    }
  };
  loadrow(0, y0 - 2);
  loadrow(1, y0 - 1);

  #pragma unroll
  for(int r = 0; r < 10; r++){
    loadrow((r + 2) % 3, y0 + r);
    // mid row r sits at global y = y0 - 1 + r; needs input rows ym-1, ym, ym+1
    int ym = y0 - 1 + r;
    int s0 = r % 3, s1 = (r + 1) % 3, s2 = (r + 2) % 3;
    bool yok = (ym >= 0) && (ym < HH);
    #pragma unroll
    for(int mx = 0; mx < 10; mx++){
      int xg = x0 - 1 + mx;
      float a = bb1;
      #pragma unroll
      for(int kx = 0; kx < 3; kx++){
        a += in[s0][mx + kx] * w1r[0 * 3 + kx];
        a += in[s1][mx + kx] * w1r[1 * 3 + kx];
        a += in[s2][mx + kx] * w1r[2 * 3 + kx];
      }
      float v = fmaxf(a, 0.f);
      if(!yok || xg < 0 || xg >= WW) v = 0.f;   // conv2 SAME-pads with 0 outside image
      mid[r % 3][mx] = v;
    }
    if(r >= 2){
      int oy = r - 2;                   // global y = y0 + oy
      int m0 = (r - 2) % 3, m1 = (r - 1) % 3, m2 = r % 3;
      #pragma unroll
      for(int ox = 0; ox < 8; ox++){
        float a = bb2;
        #pragma unroll
        for(int kx = 0; kx < 3; kx++){
          a += mid[m0][ox + kx] * w2r[0 * 3 + kx];
          a += mid[m1][ox + kx] * w2r[1 * 3 + kx];
          a += mid[m2][ox + kx] * w2r[2 * 3 + kx];
        }
        ob[((size_t)(y0 + oy) * WW + (x0 + ox)) * CC] = f2bf(a);
      }
    }
  }
}

// ---------------- gather + residual ----------------
__global__ __launch_bounds__(256) void gather_kernel(const float* tokIn, float* tokOut, const short* gridB,
                                                     const int* cell_ind, const float* occ,
                                                     const float* smScale, int g){
  int blk = blockIdx.x;
  int b   = blk >> 9;
  int n0  = (blk & 511) << 6;
  int t   = threadIdx.x;
  __shared__ float lds[256 * 65];
  __shared__ int   cellL[64];
  __shared__ float occL[64];
  if(t < 64){
    cellL[t] = cell_ind[((size_t)b * NGG + g) * NN + n0 + t];
    occL[t]  = occ[(size_t)b * NN + n0 + t];
  }
  __syncthreads();
  int half = t >> 7;
  int ch   = (t & 127) * 2;
  for(int it = 0; it < 32; it++){
    int p = it * 2 + half;
    int cell = cellL[p];
    uint32_t u = *(const uint32_t*)&gridB[((size_t)b * HWC + cell) * CC + ch];
    lds[ch * 65 + p]       = bf2f((short)(u & 0xffff));
    lds[(ch + 1) * 65 + p] = bf2f((short)(u >> 16));
  }
  __syncthreads();
  int pf = (t & 15) * 4;
  for(int i = 0; i < 16; i++){
    int c = (t >> 4) + 16 * i;
    float sc = smScale[c];
    size_t addr = ((size_t)b * CC + c) * NN + n0 + pf;
    float4 tv = *(const float4*)(tokIn + addr);
    float4 o;
    o.x = tv.x + sc * (occL[pf + 0] * lds[c * 65 + pf + 0]);
    o.y = tv.y + sc * (occL[pf + 1] * lds[c * 65 + pf + 1]);
    o.z = tv.z + sc * (occL[pf + 2] * lds[c * 65 + pf + 2]);
    o.w = tv.w + sc * (occL[pf + 3] * lds[c * 65 + pf + 3]);
    *(float4*)(tokOut + addr) = o;
  }
}

// ---------------- fold BN into W1/b1, convert W2 ----------------
__global__ __launch_bounds__(256) void fold_kernel(const float* w1, const float* bias1, const float* w2,
                                                   const float* sB, const float* tB,
                                                   short* W1f, short* W2f, float* b1f){
  int o = blockIdx.x;
  int t = threadIdx.x;
  float w = w1[(size_t)o * CC + t];
  W1f[o * CC + t] = f2bf(w * sB[t]);
  W2f[o * CC + t] = f2bf(w2[(size_t)o * CC + t]);
  __shared__ float red[256];
  red[t] = w * tB[t];
  __syncthreads();
  for(int off = 128; off > 0; off >>= 1){
    if(t < off) red[t] += red[t + off];
    __syncthreads();
  }
  if(t == 0) b1f[o] = bias1[o] + red[0];
}

// ---------------- fused MLP: tok += scale*(W2 @ relu(W1' @ tok + b1') + b2) ----------------
__global__ __launch_bounds__(256) void mlp_kernel(float* tok, const short* W1f, const float* b1f,
                                                  const short* W2f, const float* b2, const float* sc2){
  int blk = blockIdx.x;                  // B * N/64
  int b   = blk >> 9;
  int n0  = (blk & 511) << 6;
  int t   = threadIdx.x;
  int w   = t >> 6;
  int l   = t & 63;
  __shared__ short ldsX[64 * 264];       // [n][c], bf16, +8 pad
  __shared__ short ldsH[64 * 264];       // [n][o], bf16, +8 pad
  float* tb = tok + (size_t)b * CC * NN;

  // stage X tile (64 tokens x 256 channels), transpose 4x4 in regs
  {
    int nb = t & 15;
    int cbq = t >> 4;
    for(int i = 0; i < 4; i++){
      int c0 = cbq * 4 + 64 * i;
      float4 v0 = *(const float4*)(tb + (size_t)(c0 + 0) * NN + n0 + nb * 4);
      float4 v1 = *(const float4*)(tb + (size_t)(c0 + 1) * NN + n0 + nb * 4);
      float4 v2 = *(const float4*)(tb + (size_t)(c0 + 2) * NN + n0 + nb * 4);
      float4 v3 = *(const float4*)(tb + (size_t)(c0 + 3) * NN + n0 + nb * 4);
      short4v s0 = { f2bf(v0.x), f2bf(v1.x), f2bf(v2.x), f2bf(v3.x) };
      short4v s1 = { f2bf(v0.y), f2bf(v1.y), f2bf(v2.y), f2bf(v3.y) };
      short4v s2 = { f2bf(v0.z), f2bf(v1.z), f2bf(v2.z), f2bf(v3.z) };
      short4v s3 = { f2bf(v0.w), f2bf(v1.w), f2bf(v2.w), f2bf(v3.w) };
      *(short4v*)&ldsX[(nb * 4 + 0) * 264 + c0] = s0;
      *(short4v*)&ldsX[(nb * 4 + 1) * 264 + c0] = s1;
      *(short4v*)&ldsX[(nb * 4 + 2) * 264 + c0] = s2;
      *(short4v*)&ldsX[(nb * 4 + 3) * 264 + c0] = s3;
    }
  }
  __syncthreads();

  int ob = w * 64;
  int lr = l & 15;
  int lq = l >> 4;

  f32x4 acc[4][4];
  for(int m = 0; m < 4; m++)
    for(int nf = 0; nf < 4; nf++)
      acc[m][nf] = (f32x4){0.f, 0.f, 0.f, 0.f};
  for(int kk = 0; kk < 8; kk++){
    int kb = kk * 32 + lq * 8;
    short8 af[4], bfr[4];
    for(int m = 0; m < 4; m++)
      af[m] = *(const short8*)&W1f[(size_t)(ob + m * 16 + lr) * CC + kb];
    for(int nf = 0; nf < 4; nf++)
      bfr[nf] = *(const short8*)&ldsX[(nf * 16 + lr) * 264 + kb];
    for(int m = 0; m < 4; m++)
      for(int nf = 0; nf < 4; nf++)
        acc[m][nf] = __builtin_amdgcn_mfma_f32_16x16x32_bf16(af[m], bfr[nf], acc[m][nf], 0, 0, 0);
  }
  // epilogue 1: + b1', relu, bf16 -> ldsH[n][o]
  for(int m = 0; m < 4; m++){
    int o0 = ob + m * 16 + lq * 4;
    float bb0 = b1f[o0], bb1 = b1f[o0 + 1], bb2 = b1f[o0 + 2], bb3 = b1f[o0 + 3];
    for(int nf = 0; nf < 4; nf++){
      int n = nf * 16 + lr;
      short4v hv = { f2bf(fmaxf(acc[m][nf][0] + bb0, 0.f)),
                     f2bf(fmaxf(acc[m][nf][1] + bb1, 0.f)),
                     f2bf(fmaxf(acc[m][nf][2] + bb2, 0.f)),
                     f2bf(fmaxf(acc[m][nf][3] + bb3, 0.f)) };
      *(short4v*)&ldsH[n * 264 + o0] = hv;
    }
  }
  __syncthreads();

  f32x4 acc2[4][4];
  for(int m = 0; m < 4; m++)
    for(int nf = 0; nf < 4; nf++)
      acc2[m][nf] = (f32x4){0.f, 0.f, 0.f, 0.f};
  for(int kk = 0; kk < 8; kk++){
    int kb = kk * 32 + lq * 8;
    short8 af[4], bfr[4];
    for(int m = 0; m < 4; m++)
      af[m] = *(const short8*)&W2f[(size_t)(ob + m * 16 + lr) * CC + kb];
    for(int nf = 0; nf < 4; nf++)
      bfr[nf] = *(const short8*)&ldsH[(nf * 16 + lr) * 264 + kb];
    for(int m = 0; m < 4; m++)
      for(int nf = 0; nf < 4; nf++)
        acc2[m][nf] = __builtin_amdgcn_mfma_f32_16x16x32_bf16(af[m], bfr[nf], acc2[m][nf], 0, 0, 0);
  }
  // epilogue 2: tok += sc2*(acc2 + b2)
  for(int m = 0; m < 4; m++){
    int o0 = ob + m * 16 + lq * 4;
    for(int r = 0; r < 4; r++){
      int o = o0 + r;
      float s  = sc2[o];
      float bb = b2[o];
      for(int nf = 0; nf < 4; nf++){
        int n = nf * 16 + lr;
        size_t addr = (size_t)o * NN + n0 + n;
        tb[addr] = tb[addr] + s * (acc2[m][nf][r] + bb);
      }
    }
  }
}

extern "C" void kernel_launch(void* const* d_in, const int* in_sizes, int n_in,
                              void* d_out, int out_size, void* d_ws, size_t ws_size,
                              hipStream_t stream) {
  const float* tokens   = (const float*)d_in[0];
  const int*   cell_ind = (const int*)d_in[1];
  const float* occ      = (const float*)d_in[2];
  const float* cm_gamma = (const float*)d_in[3];
  const float* cm_beta  = (const float*)d_in[4];
  const float* cm_w1    = (const float*)d_in[5];
  const float* cm_b1    = (const float*)d_in[6];
  const float* cm_w2    = (const float*)d_in[7];
  const float* cm_b2    = (const float*)d_in[8];
  const float* cm_scale = (const float*)d_in[9];
  const float* sm_gamma = (const float*)d_in[10];
  const float* sm_beta  = (const float*)d_in[11];
  const float* sm_k1    = (const float*)d_in[12];
  const float* sm_b1    = (const float*)d_in[13];
  const float* sm_k2    = (const float*)d_in[14];
  const float* sm_b2    = (const float*)d_in[15];
  const float* sm_scale = (const float*)d_in[16];
  float* out = (float*)d_out;
  (void)in_sizes; (void)n_in; (void)out_size; (void)ws_size;

  char* ws = (char*)d_ws;
  size_t off = 0;
  auto carve = [&](size_t bytes) -> void* {
    void* p = ws + off;
    off = (off + bytes + 255) & ~(size_t)255;
    return p;
  };
  float* counts = (float*)carve((size_t)BB * NGG * HWC * 4);
  float* wts    = (float*)carve((size_t)BB * NGG * NN * 4);
  float* sA  = (float*)carve(CC * 4);
  float* tA  = (float*)carve(CC * 4);
  float* sB  = (float*)carve(CC * 4);
  float* tB  = (float*)carve(CC * 4);
  float* b1f = (float*)carve(CC * 4);
  short* W1f = (short*)carve((size_t)CC * CC * 2);
  short* W2f = (short*)carve((size_t)CC * CC * 2);
  float* gridA = (float*)carve((size_t)BB * HWC * CC * 4);
  short* gridB = (short*)carve((size_t)BB * HWC * CC * 2);

  hipMemsetAsync(counts, 0, (size_t)BB * NGG * HWC * 4, stream);
  count_kernel<<<BB * NGG * NN / 256, 256, 0, stream>>>(cell_ind, occ, counts);
  weight_kernel<<<BB * NGG * NN / 256, 256, 0, stream>>>(cell_ind, occ, counts, wts);

  const float* tokCur = tokens;
  for(int d = 0; d < DD; d++){
    int g = d % NGG;
    bnstats_kernel<<<CC, 256, 0, stream>>>(tokCur, sm_gamma + d * CC, sm_beta + d * CC, sA, tA);
    hipMemsetAsync(gridA, 0, (size_t)BB * HWC * CC * 4, stream);
    scatter_kernel<<<BB * NN / 64, 256, 0, stream>>>(tokCur, cell_ind, wts, sA, tA, gridA, g);
    conv_kernel<<<BB * 32 * 32, 256, 0, stream>>>(gridA, sm_k1 + (size_t)d * CC * 9, sm_b1 + d * CC,
                                                  sm_k2 + (size_t)d * CC * 9, sm_b2 + d * CC, gridB);
    gather_kernel<<<BB * NN / 64, 256, 0, stream>>>(tokCur, out, gridB, cell_ind, occ,
                                                    sm_scale + d * CC, g);
    bnstats_kernel<<<CC, 256, 0, stream>>>(out, cm_gamma + d * CC, cm_beta + d * CC, sB, tB);
    fold_kernel<<<CC, 256, 0, stream>>>(cm_w1 + (size_t)d * CC * CC, cm_b1 + d * CC,
                                        cm_w2 + (size_t)d * CC * CC, sB, tB, W1f, W2f, b1f);
    mlp_kernel<<<BB * NN / 64, 256, 0, stream>>>(out, W1f, b1f, W2f, cm_b2 + d * CC, cm_scale + d * CC);
    tokCur = out;
  }
}